// Round 5
// baseline (728.222 us; speedup 1.0000x reference)
//
#include <hip/hip_runtime.h>
#include <math.h>

#define NB    8
#define IMG   224
#define NTOK  (IMG*IMG)          // 50176 per batch
#define DIM   96
#define INR   128
#define HIDN  384
#define WT    49
#define SCALE 0.17677669529663687f

typedef __attribute__((ext_vector_type(8))) short bf16x8;
typedef __attribute__((ext_vector_type(4))) float f32x4;

#define MFMA16(a,b,c) __builtin_amdgcn_mfma_f32_16x16x32_bf16((a),(b),(c),0,0,0)

__device__ __forceinline__ short f2bf(float f) {
    unsigned u = __builtin_bit_cast(unsigned, f);
    u += 0x7fffu + ((u >> 16) & 1u);
    return (short)(u >> 16);
}

// tanh-form GELU: |err| vs exact erf-GELU ~1e-3 -> far inside threshold
__device__ __forceinline__ float gelu_f(float z) {
    const float u = z * 1.5957691216057308f * fmaf(0.044715f * z, z, 1.f);
    return z / (1.f + __expf(-u));
}

// ---------- prep: convert weights to bf16, gather rel bias (pre-scaled) ----------
__global__ void prep_kernel(const float* __restrict__ wqkv, const float* __restrict__ wout,
                            const float* __restrict__ w1,   const float* __restrict__ w2,
                            const float* __restrict__ rel_bias, char* __restrict__ ws)
{
    short* wqkvb = (short*)ws;                 // 36864 elems
    short* woutb = (short*)(ws + 73728);       // 12288
    short* w1b   = (short*)(ws + 98304);       // 36864
    short* w2b   = (short*)(ws + 172032);      // 36864
    float* biasf = (float*)(ws + 245760);      // 9604 fp32, pre-multiplied by SCALE
    const int idx = blockIdx.x * 256 + threadIdx.x;
    if      (idx < 36864)  wqkvb[idx]          = f2bf(wqkv[idx]);
    else if (idx < 49152)  woutb[idx - 36864]  = f2bf(wout[idx - 36864]);
    else if (idx < 86016)  w1b[idx - 49152]    = f2bf(w1[idx - 49152]);
    else if (idx < 122880) w2b[idx - 86016]    = f2bf(w2[idx - 86016]);
    else if (idx < 132484) {
        const int t = idx - 122880;
        const int h = t / 2401, r = t % 2401, i = r / 49, j = r % 49;
        const int rel = (i/7 - j/7 + 6) * 13 + (i%7 - j%7 + 6);
        biasf[t] = rel_bias[rel * 4 + h] * SCALE;
    }
}

// ---------- kernel 1: window attention via MFMA, one block = one 7x7 window ----------
__global__ __launch_bounds__(256, 2) void attn_kernel(
    const float* __restrict__ x, const char* __restrict__ ws,
    const float* __restrict__ b_out, const float* __restrict__ ln1_g,
    const float* __restrict__ ln1_b, float* __restrict__ y)
{
    __shared__ __align__(16) char pool[81472];
    short* hs = (short*)pool;              // [64][104]
    short* Pm = (short*)pool;              // [4][49][72], aliases hs region (hs dead by then)
    short* qs = (short*)(pool + 28224);    // [64][136], later os
    short* ks = (short*)(pool + 45632);    // [64][136]
    short* vt = (short*)(pool + 63040);    // [128][72]  (vt[dim][key])

    const short* wqkvb = (const short*)ws;
    const short* woutb = (const short*)(ws + 73728);
    const float* biasf = (const float*)(ws + 245760);

    const int tid = threadIdx.x;
    const int wv  = tid >> 6;         // wave 0..3
    const int l15 = tid & 15;
    const int l4  = (tid & 63) >> 4;
    const int wid = blockIdx.x;
    const int b = wid >> 10, xr = (wid >> 5) & 31, yr = wid & 31;

    // ---- LN1: 4 threads per row, values held in registers ----
    if (tid < 196) {
        const int i = tid >> 2, g = tid & 3;
        const float* xp = x + ((size_t)b * NTOK + (size_t)(xr*7 + i/7) * IMG + (yr*7 + i%7)) * DIM + g*24;
        float v[24]; float s = 0.f, s2 = 0.f;
        #pragma unroll
        for (int c = 0; c < 6; ++c) {
            const float4 t4 = *reinterpret_cast<const float4*>(xp + c*4);
            v[c*4+0]=t4.x; v[c*4+1]=t4.y; v[c*4+2]=t4.z; v[c*4+3]=t4.w;
            s  += t4.x + t4.y + t4.z + t4.w;
            s2 += t4.x*t4.x + t4.y*t4.y + t4.z*t4.z + t4.w*t4.w;
        }
        s  += __shfl_xor(s, 1);  s  += __shfl_xor(s, 2);
        s2 += __shfl_xor(s2, 1); s2 += __shfl_xor(s2, 2);
        const float mu = s * (1.f/96.f);
        const float rs = rsqrtf(s2 * (1.f/96.f) - mu*mu + 1e-5f);
        #pragma unroll
        for (int c = 0; c < 24; ++c) {
            const int d = g*24 + c;
            hs[i*104 + d] = f2bf((v[c] - mu) * rs * ln1_g[d] + ln1_b[d]);
        }
    }
    for (int idx = tid; idx < 15*104; idx += 256) hs[49*104 + idx] = 0;  // zero pad rows 49..63
    __syncthreads();

    // ---- qkv GEMM: h[64x96] @ Wqkv^T -> wave owns 96 output cols ----
    {
        bf16x8 afr[3][4];
        #pragma unroll
        for (int k3 = 0; k3 < 3; ++k3)
            #pragma unroll
            for (int mt = 0; mt < 4; ++mt)
                afr[k3][mt] = *reinterpret_cast<const bf16x8*>(&hs[(mt*16 + l15)*104 + k3*32 + l4*8]);
        f32x4 acc[6][4];
        #pragma unroll
        for (int nt = 0; nt < 6; ++nt)
            #pragma unroll
            for (int mt = 0; mt < 4; ++mt)
                acc[nt][mt] = (f32x4){0.f,0.f,0.f,0.f};
        #pragma unroll
        for (int nt = 0; nt < 6; ++nt) {
            const int o0 = wv*96 + nt*16;
            const short* wr = wqkvb + (size_t)(o0 + l15)*96 + l4*8;
            #pragma unroll
            for (int k3 = 0; k3 < 3; ++k3) {
                const bf16x8 bfr = *reinterpret_cast<const bf16x8*>(wr + k3*32);
                #pragma unroll
                for (int mt = 0; mt < 4; ++mt)
                    acc[nt][mt] = MFMA16(afr[k3][mt], bfr, acc[nt][mt]);
            }
        }
        #pragma unroll
        for (int nt = 0; nt < 6; ++nt) {
            const int o0 = wv*96 + nt*16;
            #pragma unroll
            for (int mt = 0; mt < 4; ++mt)
                #pragma unroll
                for (int rg = 0; rg < 4; ++rg) {
                    const int row = mt*16 + l4*4 + rg;
                    const short val = f2bf(acc[nt][mt][rg]);
                    if      (o0 < 128) qs[row*136 + o0 + l15]        = val;
                    else if (o0 < 256) ks[row*136 + o0 - 128 + l15]  = val;
                    else               vt[(o0 - 256 + l15)*72 + row] = val;
                }
        }
    }
    __syncthreads();

    // ---- S = Q K^T (wave = head), fmaf(s,SCALE,biasScaled), mask, softmax -> P ----
    {
        bf16x8 aq[4], bk[4];
        #pragma unroll
        for (int mt = 0; mt < 4; ++mt)
            aq[mt] = *reinterpret_cast<const bf16x8*>(&qs[(mt*16 + l15)*136 + wv*32 + l4*8]);
        #pragma unroll
        for (int nt = 0; nt < 4; ++nt)
            bk[nt] = *reinterpret_cast<const bf16x8*>(&ks[(nt*16 + l15)*136 + wv*32 + l4*8]);
        f32x4 s[4][4];
        #pragma unroll
        for (int mt = 0; mt < 4; ++mt)
            #pragma unroll
            for (int nt = 0; nt < 4; ++nt)
                s[mt][nt] = MFMA16(aq[mt], bk[nt], ((f32x4){0.f,0.f,0.f,0.f}));

        #pragma unroll
        for (int mt = 0; mt < 4; ++mt) {
            #pragma unroll
            for (int rg = 0; rg < 4; ++rg) {
                const int i  = mt*16 + l4*4 + rg;
                const int ic = i < WT ? i : 48;
                float vals[4];
                #pragma unroll
                for (int nt = 0; nt < 4; ++nt) {
                    const int j  = nt*16 + l15;
                    const int jc = j < WT ? j : 48;
                    const float sv = fmaf(s[mt][nt][rg], SCALE, biasf[(wv*49 + ic)*49 + jc]);
                    vals[nt] = (j < WT) ? sv : -1e30f;
                }
                float mx = fmaxf(fmaxf(vals[0], vals[1]), fmaxf(vals[2], vals[3]));
                mx = fmaxf(mx, __shfl_xor(mx, 1)); mx = fmaxf(mx, __shfl_xor(mx, 2));
                mx = fmaxf(mx, __shfl_xor(mx, 4)); mx = fmaxf(mx, __shfl_xor(mx, 8));
                float sum = 0.f;
                #pragma unroll
                for (int nt = 0; nt < 4; ++nt) { vals[nt] = __expf(vals[nt] - mx); sum += vals[nt]; }
                sum += __shfl_xor(sum, 1); sum += __shfl_xor(sum, 2);
                sum += __shfl_xor(sum, 4); sum += __shfl_xor(sum, 8);
                const float inv = 1.f / sum;
                if (i < WT) {
                    #pragma unroll
                    for (int nt = 0; nt < 4; ++nt)
                        Pm[(wv*49 + i)*72 + nt*16 + l15] = f2bf(vals[nt] * inv);
                }
            }
        }
    }
    // in-wave LDS ordering suffices (P and os column-ranges are wave-private)

    // ---- PV: o = P @ V -> os (aliases qs cols wv*32..) ----
    {
        f32x4 o[2][4];
        #pragma unroll
        for (int nt = 0; nt < 2; ++nt)
            #pragma unroll
            for (int mt = 0; mt < 4; ++mt)
                o[nt][mt] = (f32x4){0.f,0.f,0.f,0.f};
        #pragma unroll
        for (int kst = 0; kst < 2; ++kst) {
            bf16x8 bv[2];
            #pragma unroll
            for (int nt = 0; nt < 2; ++nt)
                bv[nt] = *reinterpret_cast<const bf16x8*>(&vt[(wv*32 + nt*16 + l15)*72 + kst*32 + l4*8]);
            #pragma unroll
            for (int mt = 0; mt < 4; ++mt) {
                const int rr = (mt*16 + l15) < WT ? (mt*16 + l15) : 48;
                const bf16x8 ap = *reinterpret_cast<const bf16x8*>(&Pm[(wv*49 + rr)*72 + kst*32 + l4*8]);
                #pragma unroll
                for (int nt = 0; nt < 2; ++nt)
                    o[nt][mt] = MFMA16(ap, bv[nt], o[nt][mt]);
            }
        }
        #pragma unroll
        for (int nt = 0; nt < 2; ++nt)
            #pragma unroll
            for (int mt = 0; mt < 4; ++mt)
                #pragma unroll
                for (int rg = 0; rg < 4; ++rg)
                    qs[(mt*16 + l4*4 + rg)*136 + wv*32 + nt*16 + l15] = f2bf(o[nt][mt][rg]);
    }

    // prefetch proj weights + bias while PV stores drain (global loads, LDS-independent)
    bf16x8 wofr[4][6];
    float bo6[6];
    #pragma unroll
    for (int nt = 0; nt < 6; ++nt) {
        bo6[nt] = b_out[nt*16 + l15];
        const short* wr = woutb + (size_t)(nt*16 + l15)*128 + l4*8;
        #pragma unroll
        for (int kst = 0; kst < 4; ++kst)
            wofr[kst][nt] = *reinterpret_cast<const bf16x8*>(wr + kst*32);
    }
    __syncthreads();

    // ---- proj: os[64x128] @ Wout^T + b_out + x -> y (wave = M-tile) ----
    {
        bf16x8 afr[4];
        #pragma unroll
        for (int kst = 0; kst < 4; ++kst)
            afr[kst] = *reinterpret_cast<const bf16x8*>(&qs[(wv*16 + l15)*136 + kst*32 + l4*8]);
        #pragma unroll
        for (int nt = 0; nt < 6; ++nt) {
            f32x4 acc = (f32x4){0.f,0.f,0.f,0.f};
            #pragma unroll
            for (int kst = 0; kst < 4; ++kst)
                acc = MFMA16(afr[kst], wofr[kst][nt], acc);
            #pragma unroll
            for (int rg = 0; rg < 4; ++rg) {
                const int t = wv*16 + l4*4 + rg;
                if (t < WT) {
                    const size_t gi = ((size_t)b * NTOK + (size_t)(xr*7 + t/7) * IMG + (yr*7 + t%7)) * DIM + nt*16 + l15;
                    y[gi] = acc[rg] + bo6[nt] + x[gi];
                }
            }
        }
    }
}

// ---------- kernel 2: LN2 + FFN via MFMA, 64-token tiles, 8 waves ----------
__global__ __launch_bounds__(512, 4) void ffn_kernel(
    float* __restrict__ y, const char* __restrict__ ws,
    const float* __restrict__ ln2_g, const float* __restrict__ ln2_b,
    const float* __restrict__ b1, const float* __restrict__ b2)
{
    __shared__ __align__(16) char pool[63488];
    short* h = (short*)pool;              // [64][104]
    short* t = (short*)(pool + 13312);    // [64][392]
    const short* w1b = (const short*)(ws + 98304);
    const short* w2b = (const short*)(ws + 172032);

    const int tid = threadIdx.x;
    const int wv  = tid >> 6;
    const int l15 = tid & 15;
    const int l4  = (tid & 63) >> 4;
    const size_t m0 = (size_t)blockIdx.x * 64;

    // ---- LN2: 8 threads per row ----
    {
        const int i = tid >> 3, g = tid & 7;
        const float* yp = y + (m0 + i) * DIM + g*12;
        float v[12]; float s = 0.f, s2 = 0.f;
        #pragma unroll
        for (int c = 0; c < 3; ++c) {
            const float4 t4 = *reinterpret_cast<const float4*>(yp + c*4);
            v[c*4+0]=t4.x; v[c*4+1]=t4.y; v[c*4+2]=t4.z; v[c*4+3]=t4.w;
            s  += t4.x + t4.y + t4.z + t4.w;
            s2 += t4.x*t4.x + t4.y*t4.y + t4.z*t4.z + t4.w*t4.w;
        }
        s  += __shfl_xor(s, 1);  s  += __shfl_xor(s, 2);  s  += __shfl_xor(s, 4);
        s2 += __shfl_xor(s2, 1); s2 += __shfl_xor(s2, 2); s2 += __shfl_xor(s2, 4);
        const float mu = s * (1.f/96.f);
        const float rs = rsqrtf(s2 * (1.f/96.f) - mu*mu + 1e-5f);
        #pragma unroll
        for (int c = 0; c < 12; ++c) {
            const int d = g*12 + c;
            h[i*104 + d] = f2bf((v[c] - mu) * rs * ln2_g[d] + ln2_b[d]);
        }
    }
    __syncthreads();

    // ---- GEMM1 + tanh-GELU: wave = (mt, N-half), 12 column tiles ----
    {
        const int mt = wv >> 1, nh = wv & 1;
        bf16x8 afr[3];
        #pragma unroll
        for (int k3 = 0; k3 < 3; ++k3)
            afr[k3] = *reinterpret_cast<const bf16x8*>(&h[(mt*16 + l15)*104 + k3*32 + l4*8]);
        #pragma unroll
        for (int nt = 0; nt < 12; ++nt) {
            const int o0 = nh*192 + nt*16;
            f32x4 acc = (f32x4){0.f,0.f,0.f,0.f};
            const short* wr = w1b + (size_t)(o0 + l15)*96 + l4*8;
            #pragma unroll
            for (int k3 = 0; k3 < 3; ++k3)
                acc = MFMA16(afr[k3], *reinterpret_cast<const bf16x8*>(wr + k3*32), acc);
            const float bb = b1[o0 + l15];
            #pragma unroll
            for (int rg = 0; rg < 4; ++rg)
                t[(mt*16 + l4*4 + rg)*392 + o0 + l15] = f2bf(gelu_f(acc[rg] + bb));
        }
    }
    __syncthreads();

    // ---- GEMM2 + bias + residual: wave = (mt, N-half) ----
    {
        const int mt = wv >> 1, np = wv & 1;
        float yres[3][4];
        #pragma unroll
        for (int nt = 0; nt < 3; ++nt)
            #pragma unroll
            for (int rg = 0; rg < 4; ++rg)
                yres[nt][rg] = y[(m0 + mt*16 + l4*4 + rg) * DIM + np*48 + nt*16 + l15];
        bf16x8 tfr[12];
        #pragma unroll
        for (int kst = 0; kst < 12; ++kst)
            tfr[kst] = *reinterpret_cast<const bf16x8*>(&t[(mt*16 + l15)*392 + kst*32 + l4*8]);
        #pragma unroll
        for (int nt = 0; nt < 3; ++nt) {
            const int d0 = np*48 + nt*16;
            f32x4 acc = (f32x4){0.f,0.f,0.f,0.f};
            const short* wr = w2b + (size_t)(d0 + l15)*384 + l4*8;
            #pragma unroll
            for (int kst = 0; kst < 12; ++kst)
                acc = MFMA16(tfr[kst], *reinterpret_cast<const bf16x8*>(wr + kst*32), acc);
            const float bb = b2[d0 + l15];
            #pragma unroll
            for (int rg = 0; rg < 4; ++rg)
                y[(m0 + mt*16 + l4*4 + rg) * DIM + d0 + l15] = acc[rg] + bb + yres[nt][rg];
        }
    }
}

extern "C" void kernel_launch(void* const* d_in, const int* in_sizes, int n_in,
                              void* d_out, int out_size, void* d_ws, size_t ws_size,
                              hipStream_t stream) {
    const float* x     = (const float*)d_in[0];
    const float* w_qkv = (const float*)d_in[1];
    const float* w_out = (const float*)d_in[2];
    const float* b_out = (const float*)d_in[3];
    const float* rel_b = (const float*)d_in[4];
    const float* ln1_g = (const float*)d_in[5];
    const float* ln1_b = (const float*)d_in[6];
    const float* ln2_g = (const float*)d_in[7];
    const float* ln2_b = (const float*)d_in[8];
    const float* w1    = (const float*)d_in[9];
    const float* b1    = (const float*)d_in[10];
    const float* w2    = (const float*)d_in[11];
    const float* b2    = (const float*)d_in[12];
    float* y = (float*)d_out;
    char* ws = (char*)d_ws;

    prep_kernel<<<518, 256, 0, stream>>>(w_qkv, w_out, w1, w2, rel_b, ws);
    attn_kernel<<<NB * 32 * 32, 256, 0, stream>>>(x, ws, b_out, ln1_g, ln1_b, y);
    ffn_kernel<<<(NB * NTOK) / 64, 512, 0, stream>>>(y, ws, ln2_g, ln2_b, b1, b2);
}

// Round 6
// 643.724 us; speedup vs baseline: 1.1313x; 1.1313x over previous
//
#include <hip/hip_runtime.h>
#include <math.h>

#define NB    8
#define IMG   224
#define NTOK  (IMG*IMG)          // 50176 per batch
#define DIM   96
#define INR   128
#define HIDN  384
#define WT    49
#define SCALE 0.17677669529663687f

typedef __attribute__((ext_vector_type(8))) short bf16x8;
typedef __attribute__((ext_vector_type(4))) float f32x4;
typedef __attribute__((ext_vector_type(4))) unsigned int u32x4;
typedef __attribute__((ext_vector_type(2))) unsigned long long u64x2;

#define MFMA16(a,b,c) __builtin_amdgcn_mfma_f32_16x16x32_bf16((a),(b),(c),0,0,0)

__device__ __forceinline__ short f2bf(float f) {
    unsigned u = __builtin_bit_cast(unsigned, f);
    u += 0x7fffu + ((u >> 16) & 1u);
    return (short)(u >> 16);
}

// truncating pack of two f32 -> packed bf16x2 (lo in low 16) — 3 ALU ops
__device__ __forceinline__ unsigned pktrunc(float lo, float hi) {
    return (__builtin_bit_cast(unsigned, hi) & 0xFFFF0000u) |
           (__builtin_bit_cast(unsigned, lo) >> 16);
}

// tanh-form GELU: |err| vs exact erf-GELU ~1e-3 -> far inside threshold
__device__ __forceinline__ float gelu_f(float z) {
    const float u = z * 1.5957691216057308f * fmaf(0.044715f * z, z, 1.f);
    return z / (1.f + __expf(-u));
}

// ---------- prep: convert weights to bf16, gather rel bias (pre-scaled, padded [4][49][64]) ----------
__global__ void prep_kernel(const float* __restrict__ wqkv, const float* __restrict__ wout,
                            const float* __restrict__ w1,   const float* __restrict__ w2,
                            const float* __restrict__ rel_bias, char* __restrict__ ws)
{
    short* wqkvb = (short*)ws;                 // 36864 elems
    short* woutb = (short*)(ws + 73728);       // 12288
    short* w1b   = (short*)(ws + 98304);       // 36864
    short* w2b   = (short*)(ws + 172032);      // 36864
    float* biasp = (float*)(ws + 245760);      // [4][49][64] fp32, pre-scaled, key-padded
    const int idx = blockIdx.x * 256 + threadIdx.x;
    if      (idx < 36864)  wqkvb[idx]          = f2bf(wqkv[idx]);
    else if (idx < 49152)  woutb[idx - 36864]  = f2bf(wout[idx - 36864]);
    else if (idx < 86016)  w1b[idx - 49152]    = f2bf(w1[idx - 49152]);
    else if (idx < 122880) w2b[idx - 86016]    = f2bf(w2[idx - 86016]);
    else if (idx < 135424) {
        const int t = idx - 122880;
        const int h = t / 3136, r = t % 3136, q = r / 64, k = r % 64;
        float v = 0.f;
        if (k < 49) {
            const int rel = (q/7 - k/7 + 6) * 13 + (q%7 - k%7 + 6);
            v = rel_bias[rel * 4 + h] * SCALE;
        }
        biasp[t] = v;
    }
}

// ---------- kernel 1: window attention via swapped MFMA, one block = one 7x7 window ----------
// LDS pool (bytes): [0,18432)      hs[64][104] (13312) then vt[128][72] (aliased; hs dead after A-frag loads)
//                   [18432,35840)  qs[64][136]  (q, later os)
//                   [35840,53248)  ks[64][136]
__global__ __launch_bounds__(256, 3) void attn_kernel(
    const float* __restrict__ x, const char* __restrict__ ws,
    const float* __restrict__ b_out, const float* __restrict__ ln1_g,
    const float* __restrict__ ln1_b, float* __restrict__ y)
{
    __shared__ __align__(16) char pool[53248];
    short* hs = (short*)pool;              // [64][104]
    short* vt = (short*)pool;              // [128][72]  (vt[dim][key]) — aliases hs
    short* qs = (short*)(pool + 18432);    // [64][136], later os
    short* ks = (short*)(pool + 35840);    // [64][136]

    const short* wqkvb = (const short*)ws;
    const short* woutb = (const short*)(ws + 73728);
    const float* biasp = (const float*)(ws + 245760);

    const int tid = threadIdx.x;
    const int wv  = tid >> 6;         // wave 0..3 = head
    const int l15 = tid & 15;
    const int l4  = (tid & 63) >> 4;
    const int wid = blockIdx.x;
    const int b = wid >> 10, xr = (wid >> 5) & 31, yr = wid & 31;

    // ---- LN1: 4 threads per row, values held in registers ----
    if (tid < 196) {
        const int i = tid >> 2, g = tid & 3;
        const float* xp = x + ((size_t)b * NTOK + (size_t)(xr*7 + i/7) * IMG + (yr*7 + i%7)) * DIM + g*24;
        float v[24]; float s = 0.f, s2 = 0.f;
        #pragma unroll
        for (int c = 0; c < 6; ++c) {
            const float4 t4 = *reinterpret_cast<const float4*>(xp + c*4);
            v[c*4+0]=t4.x; v[c*4+1]=t4.y; v[c*4+2]=t4.z; v[c*4+3]=t4.w;
            s  += t4.x + t4.y + t4.z + t4.w;
            s2 += t4.x*t4.x + t4.y*t4.y + t4.z*t4.z + t4.w*t4.w;
        }
        s  += __shfl_xor(s, 1);  s  += __shfl_xor(s, 2);
        s2 += __shfl_xor(s2, 1); s2 += __shfl_xor(s2, 2);
        const float mu = s * (1.f/96.f);
        const float rs = rsqrtf(s2 * (1.f/96.f) - mu*mu + 1e-5f);
        #pragma unroll
        for (int c = 0; c < 24; ++c) {
            const int d = g*24 + c;
            hs[i*104 + d] = f2bf((v[c] - mu) * rs * ln1_g[d] + ln1_b[d]);
        }
    }
    for (int idx = tid; idx < 15*104; idx += 256) hs[49*104 + idx] = 0;  // zero pad rows 49..63
    __syncthreads();   // b1

    // ---- qkv GEMM: h[64x96] @ Wqkv^T -> wave owns 96 output cols ----
    {
        bf16x8 afr[3][4];
        #pragma unroll
        for (int k3 = 0; k3 < 3; ++k3)
            #pragma unroll
            for (int mt = 0; mt < 4; ++mt)
                afr[k3][mt] = *reinterpret_cast<const bf16x8*>(&hs[(mt*16 + l15)*104 + k3*32 + l4*8]);
        f32x4 acc[6][4];
        #pragma unroll
        for (int nt = 0; nt < 6; ++nt)
            #pragma unroll
            for (int mt = 0; mt < 4; ++mt)
                acc[nt][mt] = (f32x4){0.f,0.f,0.f,0.f};
        #pragma unroll
        for (int nt = 0; nt < 6; ++nt) {
            const int o0 = wv*96 + nt*16;
            const short* wr = wqkvb + (size_t)(o0 + l15)*96 + l4*8;
            #pragma unroll
            for (int k3 = 0; k3 < 3; ++k3) {
                const bf16x8 bfr = *reinterpret_cast<const bf16x8*>(wr + k3*32);
                #pragma unroll
                for (int mt = 0; mt < 4; ++mt)
                    acc[nt][mt] = MFMA16(afr[k3][mt], bfr, acc[nt][mt]);
            }
        }
        __syncthreads();   // b2: all hs A-frag loads done before vt stores clobber the hs region
        #pragma unroll
        for (int nt = 0; nt < 6; ++nt) {
            const int o0 = wv*96 + nt*16;
            #pragma unroll
            for (int mt = 0; mt < 4; ++mt)
                #pragma unroll
                for (int rg = 0; rg < 4; ++rg) {
                    const int row = mt*16 + l4*4 + rg;
                    const short val = f2bf(acc[nt][mt][rg]);
                    if      (o0 < 128) qs[row*136 + o0 + l15]        = val;
                    else if (o0 < 256) ks[row*136 + o0 - 128 + l15]  = val;
                    else               vt[(o0 - 256 + l15)*72 + row] = val;
                }
        }
    }
    __syncthreads();   // b3

    // ---- S^T = K @ Q^T (wave = head). C-layout: lane col = query, rows = keys ----
    f32x4 st[4][4];    // [mtKey][ntQuery]
    {
        bf16x8 kf[4], qf[4];
        #pragma unroll
        for (int mt = 0; mt < 4; ++mt)
            kf[mt] = *reinterpret_cast<const bf16x8*>(&ks[(mt*16 + l15)*136 + wv*32 + l4*8]);
        #pragma unroll
        for (int nt = 0; nt < 4; ++nt)
            qf[nt] = *reinterpret_cast<const bf16x8*>(&qs[(nt*16 + l15)*136 + wv*32 + l4*8]);
        #pragma unroll
        for (int mt = 0; mt < 4; ++mt)
            #pragma unroll
            for (int nt = 0; nt < 4; ++nt)
                st[mt][nt] = MFMA16(kf[mt], qf[nt], ((f32x4){0.f,0.f,0.f,0.f}));
    }

    // ---- softmax over keys (in-lane 13 live + 2 shfl), pack P^T to bf16 pairs ----
    // lane holds, per query column (nq*16+l15), keys {mk*16 + l4*4 + rg}; keys>=49 exist only in mk=3.
    unsigned pk[4][4][2];   // [ntQuery][mtKey][pair]
    #pragma unroll
    for (int nq = 0; nq < 4; ++nq) {
        const int qc = (nq*16 + l15) < WT ? (nq*16 + l15) : 48;
        const float* bp = biasp + (wv*49 + qc)*64;
        float v[13];
        #pragma unroll
        for (int mk = 0; mk < 3; ++mk) {
            const float4 b4 = *reinterpret_cast<const float4*>(&bp[mk*16 + l4*4]);
            v[mk*4+0] = fmaf(st[mk][nq][0], SCALE, b4.x);
            v[mk*4+1] = fmaf(st[mk][nq][1], SCALE, b4.y);
            v[mk*4+2] = fmaf(st[mk][nq][2], SCALE, b4.z);
            v[mk*4+3] = fmaf(st[mk][nq][3], SCALE, b4.w);
        }
        v[12] = (l4 == 0) ? fmaf(st[3][nq][0], SCALE, bp[48]) : -1e30f;  // key 48 only
        float mx = v[0];
        #pragma unroll
        for (int t = 1; t < 13; ++t) mx = fmaxf(mx, v[t]);
        mx = fmaxf(mx, __shfl_xor(mx, 16));
        mx = fmaxf(mx, __shfl_xor(mx, 32));
        float sum = 0.f;
        #pragma unroll
        for (int t = 0; t < 13; ++t) { v[t] = __expf(v[t] - mx); sum += v[t]; }
        sum += __shfl_xor(sum, 16);
        sum += __shfl_xor(sum, 32);
        const float inv = 1.f / sum;
        #pragma unroll
        for (int mk = 0; mk < 3; ++mk) {
            pk[nq][mk][0] = pktrunc(v[mk*4+0]*inv, v[mk*4+1]*inv);
            pk[nq][mk][1] = pktrunc(v[mk*4+2]*inv, v[mk*4+3]*inv);
        }
        pk[nq][3][0] = pktrunc(v[12]*inv, 0.f);
        pk[nq][3][1] = 0u;
    }

    // ---- PV: o^T = V^T @ P^T, K permuted as (16*mk + 4*l4 + rg) on BOTH operands ----
    // A (V^T): two 8B LDS reads per frag in the permuted key order; B (P^T): pk registers directly.
    {
        f32x4 oc[2][4];   // [mtDim][ntQuery]
        #pragma unroll
        for (int md = 0; md < 2; ++md)
            #pragma unroll
            for (int nq = 0; nq < 4; ++nq)
                oc[md][nq] = (f32x4){0.f,0.f,0.f,0.f};
        #pragma unroll
        for (int kst = 0; kst < 2; ++kst) {
            bf16x8 av[2];
            #pragma unroll
            for (int md = 0; md < 2; ++md) {
                const int drow = wv*32 + md*16 + l15;
                const unsigned long long klo =
                    *reinterpret_cast<const unsigned long long*>(&vt[drow*72 + (2*kst+0)*16 + l4*4]);
                const unsigned long long khi =
                    *reinterpret_cast<const unsigned long long*>(&vt[drow*72 + (2*kst+1)*16 + l4*4]);
                av[md] = __builtin_bit_cast(bf16x8, (u64x2){klo, khi});
            }
            #pragma unroll
            for (int nq = 0; nq < 4; ++nq) {
                const bf16x8 bp8 = __builtin_bit_cast(bf16x8,
                    (u32x4){pk[nq][2*kst][0], pk[nq][2*kst][1], pk[nq][2*kst+1][0], pk[nq][2*kst+1][1]});
                #pragma unroll
                for (int md = 0; md < 2; ++md)
                    oc[md][nq] = MFMA16(av[md], bp8, oc[md][nq]);
            }
        }
        // os store (transposed back): os[query][inner]; lane: query = nq*16+l15, dims = wv*32+md*16+l4*4+{0..3}
        #pragma unroll
        for (int md = 0; md < 2; ++md)
            #pragma unroll
            for (int nq = 0; nq < 4; ++nq) {
                const unsigned lo = pktrunc(oc[md][nq][0], oc[md][nq][1]);
                const unsigned hi = pktrunc(oc[md][nq][2], oc[md][nq][3]);
                *reinterpret_cast<unsigned long long*>(
                    &qs[(nq*16 + l15)*136 + wv*32 + md*16 + l4*4]) =
                    ((unsigned long long)hi << 32) | lo;
            }
    }

    // prefetch proj weights + bias (global, LDS-independent)
    bf16x8 wofr[4][6];
    float bo6[6];
    #pragma unroll
    for (int nt = 0; nt < 6; ++nt) {
        bo6[nt] = b_out[nt*16 + l15];
        const short* wr = woutb + (size_t)(nt*16 + l15)*128 + l4*8;
        #pragma unroll
        for (int kst = 0; kst < 4; ++kst)
            wofr[kst][nt] = *reinterpret_cast<const bf16x8*>(wr + kst*32);
    }
    __syncthreads();   // b4

    // ---- proj: os[64x128] @ Wout^T + b_out + x -> y (wave = M-tile) ----
    {
        bf16x8 afr[4];
        #pragma unroll
        for (int kst = 0; kst < 4; ++kst)
            afr[kst] = *reinterpret_cast<const bf16x8*>(&qs[(wv*16 + l15)*136 + kst*32 + l4*8]);
        #pragma unroll
        for (int nt = 0; nt < 6; ++nt) {
            f32x4 acc = (f32x4){0.f,0.f,0.f,0.f};
            #pragma unroll
            for (int kst = 0; kst < 4; ++kst)
                acc = MFMA16(afr[kst], wofr[kst][nt], acc);
            #pragma unroll
            for (int rg = 0; rg < 4; ++rg) {
                const int t = wv*16 + l4*4 + rg;
                if (t < WT) {
                    const size_t gi = ((size_t)b * NTOK + (size_t)(xr*7 + t/7) * IMG + (yr*7 + t%7)) * DIM + nt*16 + l15;
                    y[gi] = acc[rg] + bo6[nt] + x[gi];
                }
            }
        }
    }
}

// ---------- kernel 2: LN2 + FFN via MFMA, 64-token tiles, 8 waves (unchanged, proven) ----------
__global__ __launch_bounds__(512, 4) void ffn_kernel(
    float* __restrict__ y, const char* __restrict__ ws,
    const float* __restrict__ ln2_g, const float* __restrict__ ln2_b,
    const float* __restrict__ b1, const float* __restrict__ b2)
{
    __shared__ __align__(16) char pool[63488];
    short* h = (short*)pool;              // [64][104]
    short* t = (short*)(pool + 13312);    // [64][392]
    const short* w1b = (const short*)(ws + 98304);
    const short* w2b = (const short*)(ws + 172032);

    const int tid = threadIdx.x;
    const int wv  = tid >> 6;
    const int l15 = tid & 15;
    const int l4  = (tid & 63) >> 4;
    const size_t m0 = (size_t)blockIdx.x * 64;

    // ---- LN2: 8 threads per row ----
    {
        const int i = tid >> 3, g = tid & 7;
        const float* yp = y + (m0 + i) * DIM + g*12;
        float v[12]; float s = 0.f, s2 = 0.f;
        #pragma unroll
        for (int c = 0; c < 3; ++c) {
            const float4 t4 = *reinterpret_cast<const float4*>(yp + c*4);
            v[c*4+0]=t4.x; v[c*4+1]=t4.y; v[c*4+2]=t4.z; v[c*4+3]=t4.w;
            s  += t4.x + t4.y + t4.z + t4.w;
            s2 += t4.x*t4.x + t4.y*t4.y + t4.z*t4.z + t4.w*t4.w;
        }
        s  += __shfl_xor(s, 1);  s  += __shfl_xor(s, 2);  s  += __shfl_xor(s, 4);
        s2 += __shfl_xor(s2, 1); s2 += __shfl_xor(s2, 2); s2 += __shfl_xor(s2, 4);
        const float mu = s * (1.f/96.f);
        const float rs = rsqrtf(s2 * (1.f/96.f) - mu*mu + 1e-5f);
        #pragma unroll
        for (int c = 0; c < 12; ++c) {
            const int d = g*12 + c;
            h[i*104 + d] = f2bf((v[c] - mu) * rs * ln2_g[d] + ln2_b[d]);
        }
    }
    __syncthreads();

    // ---- GEMM1 + tanh-GELU: wave = (mt, N-half), 12 column tiles ----
    {
        const int mt = wv >> 1, nh = wv & 1;
        bf16x8 afr[3];
        #pragma unroll
        for (int k3 = 0; k3 < 3; ++k3)
            afr[k3] = *reinterpret_cast<const bf16x8*>(&h[(mt*16 + l15)*104 + k3*32 + l4*8]);
        #pragma unroll
        for (int nt = 0; nt < 12; ++nt) {
            const int o0 = nh*192 + nt*16;
            f32x4 acc = (f32x4){0.f,0.f,0.f,0.f};
            const short* wr = w1b + (size_t)(o0 + l15)*96 + l4*8;
            #pragma unroll
            for (int k3 = 0; k3 < 3; ++k3)
                acc = MFMA16(afr[k3], *reinterpret_cast<const bf16x8*>(wr + k3*32), acc);
            const float bb = b1[o0 + l15];
            #pragma unroll
            for (int rg = 0; rg < 4; ++rg)
                t[(mt*16 + l4*4 + rg)*392 + o0 + l15] = f2bf(gelu_f(acc[rg] + bb));
        }
    }
    __syncthreads();

    // ---- GEMM2 + bias + residual: wave = (mt, N-half) ----
    {
        const int mt = wv >> 1, np = wv & 1;
        float yres[3][4];
        #pragma unroll
        for (int nt = 0; nt < 3; ++nt)
            #pragma unroll
            for (int rg = 0; rg < 4; ++rg)
                yres[nt][rg] = y[(m0 + mt*16 + l4*4 + rg) * DIM + np*48 + nt*16 + l15];
        bf16x8 tfr[12];
        #pragma unroll
        for (int kst = 0; kst < 12; ++kst)
            tfr[kst] = *reinterpret_cast<const bf16x8*>(&t[(mt*16 + l15)*392 + kst*32 + l4*8]);
        #pragma unroll
        for (int nt = 0; nt < 3; ++nt) {
            const int d0 = np*48 + nt*16;
            f32x4 acc = (f32x4){0.f,0.f,0.f,0.f};
            const short* wr = w2b + (size_t)(d0 + l15)*384 + l4*8;
            #pragma unroll
            for (int kst = 0; kst < 12; ++kst)
                acc = MFMA16(tfr[kst], *reinterpret_cast<const bf16x8*>(wr + kst*32), acc);
            const float bb = b2[d0 + l15];
            #pragma unroll
            for (int rg = 0; rg < 4; ++rg)
                y[(m0 + mt*16 + l4*4 + rg) * DIM + d0 + l15] = acc[rg] + bb + yres[nt][rg];
        }
    }
}

extern "C" void kernel_launch(void* const* d_in, const int* in_sizes, int n_in,
                              void* d_out, int out_size, void* d_ws, size_t ws_size,
                              hipStream_t stream) {
    const float* x     = (const float*)d_in[0];
    const float* w_qkv = (const float*)d_in[1];
    const float* w_out = (const float*)d_in[2];
    const float* b_out = (const float*)d_in[3];
    const float* rel_b = (const float*)d_in[4];
    const float* ln1_g = (const float*)d_in[5];
    const float* ln1_b = (const float*)d_in[6];
    const float* ln2_g = (const float*)d_in[7];
    const float* ln2_b = (const float*)d_in[8];
    const float* w1    = (const float*)d_in[9];
    const float* b1    = (const float*)d_in[10];
    const float* w2    = (const float*)d_in[11];
    const float* b2    = (const float*)d_in[12];
    float* y = (float*)d_out;
    char* ws = (char*)d_ws;

    prep_kernel<<<529, 256, 0, stream>>>(w_qkv, w_out, w1, w2, rel_b, ws);
    attn_kernel<<<NB * 32 * 32, 256, 0, stream>>>(x, ws, b_out, ln1_g, ln1_b, y);
    ffn_kernel<<<(NB * NTOK) / 64, 512, 0, stream>>>(y, ws, ln2_g, ln2_b, b1, b2);
}

// Round 7
// 616.627 us; speedup vs baseline: 1.1810x; 1.0439x over previous
//
#include <hip/hip_runtime.h>
#include <math.h>

#define NB    8
#define IMG   224
#define NTOK  (IMG*IMG)          // 50176 per batch
#define DIM   96
#define INR   128
#define HIDN  384
#define WT    49
#define SCALE 0.17677669529663687f

typedef __attribute__((ext_vector_type(8))) short bf16x8;
typedef __attribute__((ext_vector_type(4))) float f32x4;
typedef __attribute__((ext_vector_type(4))) unsigned int u32x4;
typedef __attribute__((ext_vector_type(2))) unsigned long long u64x2;

#define MFMA16(a,b,c) __builtin_amdgcn_mfma_f32_16x16x32_bf16((a),(b),(c),0,0,0)

__device__ __forceinline__ short f2bf(float f) {
    unsigned u = __builtin_bit_cast(unsigned, f);
    u += 0x7fffu + ((u >> 16) & 1u);
    return (short)(u >> 16);
}

// truncating pack of two f32 -> packed bf16x2 (lo in low 16) — 3 ALU ops
__device__ __forceinline__ unsigned pktrunc(float lo, float hi) {
    return (__builtin_bit_cast(unsigned, hi) & 0xFFFF0000u) |
           (__builtin_bit_cast(unsigned, lo) >> 16);
}

// tanh-form GELU: |err| vs exact erf-GELU ~1e-3 -> far inside threshold
__device__ __forceinline__ float gelu_f(float z) {
    const float u = z * 1.5957691216057308f * fmaf(0.044715f * z, z, 1.f);
    return z / (1.f + __expf(-u));
}

// ---------- prep: convert weights to bf16, gather rel bias (pre-scaled, padded [4][49][64]) ----------
__global__ void prep_kernel(const float* __restrict__ wqkv, const float* __restrict__ wout,
                            const float* __restrict__ w1,   const float* __restrict__ w2,
                            const float* __restrict__ rel_bias, char* __restrict__ ws)
{
    short* wqkvb = (short*)ws;                 // 36864 elems
    short* woutb = (short*)(ws + 73728);       // 12288
    short* w1b   = (short*)(ws + 98304);       // 36864
    short* w2b   = (short*)(ws + 172032);      // 36864
    float* biasp = (float*)(ws + 245760);      // [4][49][64] fp32, pre-scaled, key-padded
    const int idx = blockIdx.x * 256 + threadIdx.x;
    if      (idx < 36864)  wqkvb[idx]          = f2bf(wqkv[idx]);
    else if (idx < 49152)  woutb[idx - 36864]  = f2bf(wout[idx - 36864]);
    else if (idx < 86016)  w1b[idx - 49152]    = f2bf(w1[idx - 49152]);
    else if (idx < 122880) w2b[idx - 86016]    = f2bf(w2[idx - 86016]);
    else if (idx < 135424) {
        const int t = idx - 122880;
        const int h = t / 3136, r = t % 3136, q = r / 64, k = r % 64;
        float v = 0.f;
        if (k < 49) {
            const int rel = (q/7 - k/7 + 6) * 13 + (q%7 - k%7 + 6);
            v = rel_bias[rel * 4 + h] * SCALE;
        }
        biasp[t] = v;
    }
}

// ---------- fused kernel: LN1+qkv+attn+proj+LN2+FFN, one block = one 7x7 window ----------
// LDS pool (bytes), attn stage:
//   [0,18432)      hs[64][104] (13312) then vt[128][72] (aliased)
//   [18432,35840)  qs[64][136]  (q, later os)
//   [35840,53248)  ks[64][136]
// FFN stage (all attn buffers dead after proj A-frag loads):
//   [0,13312)      h2[64][104]   (LN2 output)
//   [27648,53248)  ts[64][200]   (GELU'd GEMM1 half, 192 cols + pad)
__global__ __launch_bounds__(256, 3) void fused_kernel(
    const float* __restrict__ x, const char* __restrict__ ws,
    const float* __restrict__ b_out, const float* __restrict__ ln1_g,
    const float* __restrict__ ln1_b, const float* __restrict__ ln2_g,
    const float* __restrict__ ln2_b, const float* __restrict__ b1,
    const float* __restrict__ b2, float* __restrict__ y)
{
    __shared__ __align__(16) char pool[53248];
    short* hs = (short*)pool;              // [64][104]
    short* vt = (short*)pool;              // [128][72]  (vt[dim][key]) — aliases hs
    short* qs = (short*)(pool + 18432);    // [64][136], later os
    short* ks = (short*)(pool + 35840);    // [64][136]
    short* h2 = (short*)pool;              // [64][104]  FFN stage
    short* ts = (short*)(pool + 27648);    // [64][200]  FFN stage

    const short* wqkvb = (const short*)ws;
    const short* woutb = (const short*)(ws + 73728);
    const short* w1b   = (const short*)(ws + 98304);
    const short* w2b   = (const short*)(ws + 172032);
    const float* biasp = (const float*)(ws + 245760);

    const int tid = threadIdx.x;
    const int wv  = tid >> 6;         // wave 0..3 (= head in attn, = M-tile in proj/FFN)
    const int l15 = tid & 15;
    const int l4  = (tid & 63) >> 4;
    const int wid = blockIdx.x;
    const int b = wid >> 10, xr = (wid >> 5) & 31, yr = wid & 31;

    // ---- LN1: 4 threads per row, values held in registers ----
    if (tid < 196) {
        const int i = tid >> 2, g = tid & 3;
        const float* xp = x + ((size_t)b * NTOK + (size_t)(xr*7 + i/7) * IMG + (yr*7 + i%7)) * DIM + g*24;
        float v[24]; float s = 0.f, s2 = 0.f;
        #pragma unroll
        for (int c = 0; c < 6; ++c) {
            const float4 t4 = *reinterpret_cast<const float4*>(xp + c*4);
            v[c*4+0]=t4.x; v[c*4+1]=t4.y; v[c*4+2]=t4.z; v[c*4+3]=t4.w;
            s  += t4.x + t4.y + t4.z + t4.w;
            s2 += t4.x*t4.x + t4.y*t4.y + t4.z*t4.z + t4.w*t4.w;
        }
        s  += __shfl_xor(s, 1);  s  += __shfl_xor(s, 2);
        s2 += __shfl_xor(s2, 1); s2 += __shfl_xor(s2, 2);
        const float mu = s * (1.f/96.f);
        const float rs = rsqrtf(s2 * (1.f/96.f) - mu*mu + 1e-5f);
        #pragma unroll
        for (int c = 0; c < 24; ++c) {
            const int d = g*24 + c;
            hs[i*104 + d] = f2bf((v[c] - mu) * rs * ln1_g[d] + ln1_b[d]);
        }
    }
    for (int idx = tid; idx < 15*104; idx += 256) hs[49*104 + idx] = 0;  // zero pad rows 49..63
    __syncthreads();   // b1

    // ---- qkv GEMM: h[64x96] @ Wqkv^T -> wave owns 96 output cols ----
    {
        bf16x8 afr[3][4];
        #pragma unroll
        for (int k3 = 0; k3 < 3; ++k3)
            #pragma unroll
            for (int mt = 0; mt < 4; ++mt)
                afr[k3][mt] = *reinterpret_cast<const bf16x8*>(&hs[(mt*16 + l15)*104 + k3*32 + l4*8]);
        f32x4 acc[6][4];
        #pragma unroll
        for (int nt = 0; nt < 6; ++nt)
            #pragma unroll
            for (int mt = 0; mt < 4; ++mt)
                acc[nt][mt] = (f32x4){0.f,0.f,0.f,0.f};
        #pragma unroll
        for (int nt = 0; nt < 6; ++nt) {
            const int o0 = wv*96 + nt*16;
            const short* wr = wqkvb + (size_t)(o0 + l15)*96 + l4*8;
            #pragma unroll
            for (int k3 = 0; k3 < 3; ++k3) {
                const bf16x8 bfr = *reinterpret_cast<const bf16x8*>(wr + k3*32);
                #pragma unroll
                for (int mt = 0; mt < 4; ++mt)
                    acc[nt][mt] = MFMA16(afr[k3][mt], bfr, acc[nt][mt]);
            }
        }
        __syncthreads();   // b2: all hs A-frag loads done before vt stores clobber hs region
        #pragma unroll
        for (int nt = 0; nt < 6; ++nt) {
            const int o0 = wv*96 + nt*16;
            #pragma unroll
            for (int mt = 0; mt < 4; ++mt)
                #pragma unroll
                for (int rg = 0; rg < 4; ++rg) {
                    const int row = mt*16 + l4*4 + rg;
                    const short val = f2bf(acc[nt][mt][rg]);
                    if      (o0 < 128) qs[row*136 + o0 + l15]        = val;
                    else if (o0 < 256) ks[row*136 + o0 - 128 + l15]  = val;
                    else               vt[(o0 - 256 + l15)*72 + row] = val;
                }
        }
    }
    __syncthreads();   // b3

    // ---- S^T = K @ Q^T (wave = head). C-layout: lane col = query, rows = keys ----
    f32x4 st[4][4];    // [mtKey][ntQuery]
    {
        bf16x8 kf[4], qf[4];
        #pragma unroll
        for (int mt = 0; mt < 4; ++mt)
            kf[mt] = *reinterpret_cast<const bf16x8*>(&ks[(mt*16 + l15)*136 + wv*32 + l4*8]);
        #pragma unroll
        for (int nt = 0; nt < 4; ++nt)
            qf[nt] = *reinterpret_cast<const bf16x8*>(&qs[(nt*16 + l15)*136 + wv*32 + l4*8]);
        #pragma unroll
        for (int mt = 0; mt < 4; ++mt)
            #pragma unroll
            for (int nt = 0; nt < 4; ++nt)
                st[mt][nt] = MFMA16(kf[mt], qf[nt], ((f32x4){0.f,0.f,0.f,0.f}));
    }

    // ---- softmax over keys (in-lane 13 live + 2 shfl), pack P^T to bf16 pairs ----
    unsigned pk[4][4][2];   // [ntQuery][mtKey][pair]
    #pragma unroll
    for (int nq = 0; nq < 4; ++nq) {
        const int qc = (nq*16 + l15) < WT ? (nq*16 + l15) : 48;
        const float* bp = biasp + (wv*49 + qc)*64;
        float v[13];
        #pragma unroll
        for (int mk = 0; mk < 3; ++mk) {
            const float4 b4 = *reinterpret_cast<const float4*>(&bp[mk*16 + l4*4]);
            v[mk*4+0] = fmaf(st[mk][nq][0], SCALE, b4.x);
            v[mk*4+1] = fmaf(st[mk][nq][1], SCALE, b4.y);
            v[mk*4+2] = fmaf(st[mk][nq][2], SCALE, b4.z);
            v[mk*4+3] = fmaf(st[mk][nq][3], SCALE, b4.w);
        }
        v[12] = (l4 == 0) ? fmaf(st[3][nq][0], SCALE, bp[48]) : -1e30f;  // key 48 only
        float mx = v[0];
        #pragma unroll
        for (int t = 1; t < 13; ++t) mx = fmaxf(mx, v[t]);
        mx = fmaxf(mx, __shfl_xor(mx, 16));
        mx = fmaxf(mx, __shfl_xor(mx, 32));
        float sum = 0.f;
        #pragma unroll
        for (int t = 0; t < 13; ++t) { v[t] = __expf(v[t] - mx); sum += v[t]; }
        sum += __shfl_xor(sum, 16);
        sum += __shfl_xor(sum, 32);
        const float inv = 1.f / sum;
        #pragma unroll
        for (int mk = 0; mk < 3; ++mk) {
            pk[nq][mk][0] = pktrunc(v[mk*4+0]*inv, v[mk*4+1]*inv);
            pk[nq][mk][1] = pktrunc(v[mk*4+2]*inv, v[mk*4+3]*inv);
        }
        pk[nq][3][0] = pktrunc(v[12]*inv, 0.f);
        pk[nq][3][1] = 0u;
    }

    // ---- PV: o^T = V^T @ P^T, K permuted as (16*mk + 4*l4 + rg) on BOTH operands ----
    {
        f32x4 oc[2][4];   // [mtDim][ntQuery]
        #pragma unroll
        for (int md = 0; md < 2; ++md)
            #pragma unroll
            for (int nq = 0; nq < 4; ++nq)
                oc[md][nq] = (f32x4){0.f,0.f,0.f,0.f};
        #pragma unroll
        for (int kst = 0; kst < 2; ++kst) {
            bf16x8 av[2];
            #pragma unroll
            for (int md = 0; md < 2; ++md) {
                const int drow = wv*32 + md*16 + l15;
                const unsigned long long klo =
                    *reinterpret_cast<const unsigned long long*>(&vt[drow*72 + (2*kst+0)*16 + l4*4]);
                const unsigned long long khi =
                    *reinterpret_cast<const unsigned long long*>(&vt[drow*72 + (2*kst+1)*16 + l4*4]);
                av[md] = __builtin_bit_cast(bf16x8, (u64x2){klo, khi});
            }
            #pragma unroll
            for (int nq = 0; nq < 4; ++nq) {
                const bf16x8 bp8 = __builtin_bit_cast(bf16x8,
                    (u32x4){pk[nq][2*kst][0], pk[nq][2*kst][1], pk[nq][2*kst+1][0], pk[nq][2*kst+1][1]});
                #pragma unroll
                for (int md = 0; md < 2; ++md)
                    oc[md][nq] = MFMA16(av[md], bp8, oc[md][nq]);
            }
        }
        // os store (transposed back): os[query][inner]
        #pragma unroll
        for (int md = 0; md < 2; ++md)
            #pragma unroll
            for (int nq = 0; nq < 4; ++nq) {
                const unsigned lo = pktrunc(oc[md][nq][0], oc[md][nq][1]);
                const unsigned hi = pktrunc(oc[md][nq][2], oc[md][nq][3]);
                *reinterpret_cast<unsigned long long*>(
                    &qs[(nq*16 + l15)*136 + wv*32 + md*16 + l4*4]) =
                    ((unsigned long long)hi << 32) | lo;
            }
    }

    // prefetch proj weights + biases + LN2 params (global, LDS-independent)
    bf16x8 wofr[4][6];
    float bo6[6], g6[6], be6[6], b26[6];
    #pragma unroll
    for (int nt = 0; nt < 6; ++nt) {
        bo6[nt] = b_out[nt*16 + l15];
        g6[nt]  = ln2_g[nt*16 + l15];
        be6[nt] = ln2_b[nt*16 + l15];
        b26[nt] = b2[nt*16 + l15];
        const short* wr = woutb + (size_t)(nt*16 + l15)*128 + l4*8;
        #pragma unroll
        for (int kst = 0; kst < 4; ++kst)
            wofr[kst][nt] = *reinterpret_cast<const bf16x8*>(wr + kst*32);
    }
    __syncthreads();   // b4

    // ---- proj: os[64x128] @ Wout^T + b_out + x -> yreg (kept in registers) ----
    // thread holds rows wv*16 + l4*4 + {0..3}, cols nt*16 + l15
    float yreg[6][4];
    {
        bf16x8 afr[4];
        #pragma unroll
        for (int kst = 0; kst < 4; ++kst)
            afr[kst] = *reinterpret_cast<const bf16x8*>(&qs[(wv*16 + l15)*136 + kst*32 + l4*8]);
        #pragma unroll
        for (int nt = 0; nt < 6; ++nt) {
            f32x4 acc = (f32x4){0.f,0.f,0.f,0.f};
            #pragma unroll
            for (int kst = 0; kst < 4; ++kst)
                acc = MFMA16(afr[kst], wofr[kst][nt], acc);
            #pragma unroll
            for (int rg = 0; rg < 4; ++rg) {
                const int tok = wv*16 + l4*4 + rg;
                float r = acc[rg] + bo6[nt];
                if (tok < WT) {
                    const size_t gi = ((size_t)b * NTOK + (size_t)(xr*7 + tok/7) * IMG + (yr*7 + tok%7)) * DIM + nt*16 + l15;
                    r += x[gi];
                }
                yreg[nt][rg] = r;
            }
        }
    }

    // ---- LN2 fully in-register: row spread over 16 l15-lanes x 6 nt ----
    float mu4[4], rs4[4];
    #pragma unroll
    for (int rg = 0; rg < 4; ++rg) {
        float s = 0.f, s2 = 0.f;
        #pragma unroll
        for (int nt = 0; nt < 6; ++nt) { const float v = yreg[nt][rg]; s += v; s2 += v*v; }
        s  += __shfl_xor(s, 1);  s  += __shfl_xor(s, 2);  s  += __shfl_xor(s, 4);  s  += __shfl_xor(s, 8);
        s2 += __shfl_xor(s2, 1); s2 += __shfl_xor(s2, 2); s2 += __shfl_xor(s2, 4); s2 += __shfl_xor(s2, 8);
        const float m = s * (1.f/96.f);
        mu4[rg] = m;
        rs4[rg] = rsqrtf(s2 * (1.f/96.f) - m*m + 1e-5f);
    }
    #pragma unroll
    for (int nt = 0; nt < 6; ++nt)
        #pragma unroll
        for (int rg = 0; rg < 4; ++rg)
            h2[(wv*16 + l4*4 + rg)*104 + nt*16 + l15] =
                f2bf((yreg[nt][rg] - mu4[rg]) * rs4[rg] * g6[nt] + be6[nt]);
    __syncthreads();   // b5: h2 ready (garbage rows >=49 are finite and confined)

    // ---- FFN: GEMM1 (two 192-col halves, GELU -> ts) interleaved with GEMM2 k-partials ----
    f32x4 acc2[6];
    #pragma unroll
    for (int nt = 0; nt < 6; ++nt) acc2[nt] = (f32x4){0.f,0.f,0.f,0.f};

    #pragma unroll
    for (int al = 0; al < 2; ++al) {
        // A-frags from h2 (reload per half to relieve VGPR pressure)
        bf16x8 af[3][4];
        #pragma unroll
        for (int k3 = 0; k3 < 3; ++k3)
            #pragma unroll
            for (int mt = 0; mt < 4; ++mt)
                af[k3][mt] = *reinterpret_cast<const bf16x8*>(&h2[(mt*16 + l15)*104 + k3*32 + l4*8]);
        // GEMM1: wave owns cols al*192 + wv*48 + {0..47}
        #pragma unroll
        for (int n3 = 0; n3 < 3; ++n3) {
            const int c0 = al*192 + wv*48 + n3*16;
            const short* wr = w1b + (size_t)(c0 + l15)*96 + l4*8;
            f32x4 a1[4];
            #pragma unroll
            for (int mt = 0; mt < 4; ++mt) a1[mt] = (f32x4){0.f,0.f,0.f,0.f};
            #pragma unroll
            for (int k3 = 0; k3 < 3; ++k3) {
                const bf16x8 bf = *reinterpret_cast<const bf16x8*>(wr + k3*32);
                #pragma unroll
                for (int mt = 0; mt < 4; ++mt)
                    a1[mt] = MFMA16(af[k3][mt], bf, a1[mt]);
            }
            const float bb = b1[c0 + l15];
            #pragma unroll
            for (int mt = 0; mt < 4; ++mt)
                #pragma unroll
                for (int rg = 0; rg < 4; ++rg)
                    ts[(mt*16 + l4*4 + rg)*200 + wv*48 + n3*16 + l15] = f2bf(gelu_f(a1[mt][rg] + bb));
        }
        __syncthreads();   // b6/b8: ts half ready
        // GEMM2 partial: wave = M-tile, k = al*192 + kl*32
        bf16x8 at[6];
        #pragma unroll
        for (int kl = 0; kl < 6; ++kl)
            at[kl] = *reinterpret_cast<const bf16x8*>(&ts[(wv*16 + l15)*200 + kl*32 + l4*8]);
        #pragma unroll
        for (int nt = 0; nt < 6; ++nt) {
            const short* wr2 = w2b + (size_t)(nt*16 + l15)*384 + al*192 + l4*8;
            #pragma unroll
            for (int kl = 0; kl < 6; ++kl)
                acc2[nt] = MFMA16(at[kl], *reinterpret_cast<const bf16x8*>(wr2 + kl*32), acc2[nt]);
        }
        if (al == 0) __syncthreads();   // b7: ts reads done before half-1 overwrites
    }

    // ---- final: y = gemm2 + b2 + yreg (residual in-register), single global write ----
    #pragma unroll
    for (int nt = 0; nt < 6; ++nt)
        #pragma unroll
        for (int rg = 0; rg < 4; ++rg) {
            const int tok = wv*16 + l4*4 + rg;
            if (tok < WT) {
                const size_t gi = ((size_t)b * NTOK + (size_t)(xr*7 + tok/7) * IMG + (yr*7 + tok%7)) * DIM + nt*16 + l15;
                y[gi] = acc2[nt][rg] + b26[nt] + yreg[nt][rg];
            }
        }
}

extern "C" void kernel_launch(void* const* d_in, const int* in_sizes, int n_in,
                              void* d_out, int out_size, void* d_ws, size_t ws_size,
                              hipStream_t stream) {
    const float* x     = (const float*)d_in[0];
    const float* w_qkv = (const float*)d_in[1];
    const float* w_out = (const float*)d_in[2];
    const float* b_out = (const float*)d_in[3];
    const float* rel_b = (const float*)d_in[4];
    const float* ln1_g = (const float*)d_in[5];
    const float* ln1_b = (const float*)d_in[6];
    const float* ln2_g = (const float*)d_in[7];
    const float* ln2_b = (const float*)d_in[8];
    const float* w1    = (const float*)d_in[9];
    const float* b1    = (const float*)d_in[10];
    const float* w2    = (const float*)d_in[11];
    const float* b2    = (const float*)d_in[12];
    float* y = (float*)d_out;
    char* ws = (char*)d_ws;

    prep_kernel<<<529, 256, 0, stream>>>(w_qkv, w_out, w1, w2, rel_b, ws);
    fused_kernel<<<NB * 32 * 32, 256, 0, stream>>>(x, ws, b_out, ln1_g, ln1_b,
                                                   ln2_g, ln2_b, b1, b2, y);
}